// Round 4
// baseline (918.652 us; speedup 1.0000x reference)
//
#include <hip/hip_runtime.h>
#include <hip/hip_bf16.h>

// SelMul: out[b,o] = sum_{i<=j} x[b,i]*x[b,j]*W[o, idx(i,j)]
// B=256, D=512, OUT=1024, H=131328.
// GEMM: packed(256 x 131328) @ W^T, A generated on the fly (segment i:
// A[b,k]=x[b,i]*x[b,j], scale folded at staging). BM=256 -> W read once
// (538 MB = 85us HBM floor).
//
// R3 lesson: 1 block/CU + barrier lockstep = zero latency hiding (selmul
// ~320us, per-step wall ~6200cyc vs ~600cyc of work). Fix: 3 independent
// barrier groups per CU. 256-thr blocks (4 waves), BN=64, grid 16x64=1024,
// ~140 VGPR (-> 3 blocks/CU). W keeps a 1-deep register prefetch + raw
// s_barrier (no vmcnt drain); A (L2-resident x) loaded in-phase, hidden by
// sibling blocks.

#define DDIM 512
#define ODIM 1024
#define HDIM 131328L
#define NT 16        // N tiles of 64
#define NSPLIT 64    // k-split blocks; pairing i={s+128t,127-s+128t} -> 68 steps each
#define AST 40       // A LDS row stride (bf16): 32+8 pad, 80 B rows
#define WST 40

typedef __attribute__((ext_vector_type(4))) float floatx4;
typedef __attribute__((ext_vector_type(8))) short short8;
typedef floatx4 __attribute__((aligned(4))) floatx4u;

__device__ inline floatx4 load4u(const float* p) { return *(const floatx4u*)p; }

__device__ inline unsigned short f2bf(float v) {
    return __builtin_bit_cast(unsigned short, __float2bfloat16(v));
}
__device__ inline unsigned f2bf2(float a, float b) {
    return (unsigned)f2bf(a) | ((unsigned)f2bf(b) << 16);
}

// Raw barriers: do NOT drain vmcnt (W prefetch stays in flight).
#define BAR_PLAIN() asm volatile("s_barrier" ::: "memory")
#define BAR_LGKM()  asm volatile("s_waitcnt lgkmcnt(0)\n\ts_barrier" ::: "memory")

__global__ __launch_bounds__(256, 3) void selmul_kernel(const float* __restrict__ x,
                                                        const float* __restrict__ W,
                                                        float* __restrict__ part) {
    __shared__ __align__(16) unsigned short A_lds[256 * AST];
    __shared__ __align__(16) unsigned short W_lds[64 * WST];

    const int t    = threadIdx.x;
    const int lane = t & 63;
    const int wave = t >> 6;            // 0..3
    const int wm   = wave * 64;         // wave row offset (256 rows / 4 waves)
    const int l15  = lane & 15;
    const int quad = lane >> 4;

    const int n0 = blockIdx.x * 64;     // 16 N-tiles of 64
    const int s  = blockIdx.y;          // 0..63 k-split

    // staging decomposition: 4-col group c4 (cols c4*4..+3), row group rv
    const int c4 = t & 7;
    const int rv = t >> 3;              // 0..31

    floatx4 acc[4][4] = {};             // wave tile 64x64 = 4x4 16x16 frags
    floatx4 wv[2];                      // W prefetch (1-deep)
    float   xi[8];

    auto mfma_phase = [&]() {
        short8 af[4], bw[4];
        #pragma unroll
        for (int fm = 0; fm < 4; ++fm)
            af[fm] = *(const short8*)&A_lds[(wm + fm * 16 + l15) * AST + quad * 8];
        #pragma unroll
        for (int fn = 0; fn < 4; ++fn)
            bw[fn] = *(const short8*)&W_lds[(fn * 16 + l15) * WST + quad * 8];
        #pragma unroll
        for (int fm = 0; fm < 4; ++fm)
            #pragma unroll
            for (int fn = 0; fn < 4; ++fn)
                acc[fm][fn] = __builtin_amdgcn_mfma_f32_16x16x32_bf16(
                    af[fm], bw[fn], acc[fm][fn], 0, 0, 0);
    };

    for (int tseg = 0; tseg < 8; ++tseg) {
        const int t4   = tseg >> 1;
        const int i    = (tseg & 1) ? (127 - s + 128 * t4) : (s + 128 * t4);
        const int len  = DDIM - i;
        const long base = (long)i * DDIM - (long)i * (i - 1) / 2;
        const int full = len >> 5;
        const int rem  = len & 31;

        // per-segment scale column (L2-hot)
        #pragma unroll
        for (int e = 0; e < 8; ++e)
            xi[e] = x[(rv + 32 * e) * DDIM + i];

        if (full > 0) {
            const float* axp = x + rv * DDIM + i + c4 * 4;
            const float* wpp = W + (long)(n0 + rv) * HDIM + base + c4 * 4;
            // prefetch W step 0
            #pragma unroll
            for (int e = 0; e < 2; ++e) wv[e] = load4u(wpp + (long)e * 32 * HDIM);
            wpp += 32;

            for (int st = 0; st < full; ++st) {
                BAR_PLAIN();   // prev MFMA's LDS reads already lgkm-drained by consumers
                // A loads for this step (L2: x resident) — issued first, consumed last
                floatx4 av[8];
                #pragma unroll
                for (int e = 0; e < 8; ++e) av[e] = load4u(axp + e * 32 * DDIM);
                axp += 32;
                // store W from prefetched regs (waits only on old W loads)
                #pragma unroll
                for (int e = 0; e < 2; ++e) {
                    floatx4 v = wv[e];
                    uint2 p;
                    p.x = f2bf2(v.x, v.y);
                    p.y = f2bf2(v.z, v.w);
                    *(uint2*)&W_lds[(rv + 32 * e) * WST + c4 * 4] = p;
                }
                // issue next step's W prefetch; stays in flight through MFMA
                if (st + 1 < full) {
                    #pragma unroll
                    for (int e = 0; e < 2; ++e) wv[e] = load4u(wpp + (long)e * 32 * HDIM);
                    wpp += 32;
                }
                // convert+store A (progressive vmcnt waits on av)
                #pragma unroll
                for (int e = 0; e < 8; ++e) {
                    floatx4 v = av[e];
                    const float sc = xi[e];
                    uint2 p;
                    p.x = f2bf2(v.x * sc, v.y * sc);
                    p.y = f2bf2(v.z * sc, v.w * sc);
                    *(uint2*)&A_lds[(rv + 32 * e) * AST + c4 * 4] = p;
                }
                BAR_LGKM();    // LDS writes visible; vmcnt NOT drained
                mfma_phase();
            }
        }

        if (rem) {
            // masked tail step (scalar, <=1 per segment)
            const int jj = t & 31;
            const int rb = t >> 5;          // 0..7
            const int j0 = i + full * 32;
            const bool valid = jj < rem;
            const int j = valid ? (j0 + jj) : i;
            const long kc = base + (long)full * 32;
            BAR_PLAIN();
            #pragma unroll
            for (int e = 0; e < 32; ++e) {
                const int m = rb + 8 * e;
                float a = valid ? x[m * DDIM + j] * x[m * DDIM + i] : 0.0f;
                A_lds[m * AST + jj] = f2bf(a);
            }
            #pragma unroll
            for (int e = 0; e < 8; ++e) {
                const int n = rb + 8 * e;
                const long ks = valid ? (kc + jj) : base;
                W_lds[n * WST + jj] = f2bf(W[(long)(n0 + n) * HDIM + ks]);
            }
            BAR_LGKM();
            mfma_phase();
        }
    }

    // partial store: part[s][row][col]
    float* po = part + (long)s * (256 * ODIM);
    #pragma unroll
    for (int fm = 0; fm < 4; ++fm) {
        const int row = wm + fm * 16 + quad * 4;
        #pragma unroll
        for (int fn = 0; fn < 4; ++fn) {
            const int col = n0 + fn * 16 + l15;
            #pragma unroll
            for (int r = 0; r < 4; ++r)
                po[(row + r) * ODIM + col] = acc[fm][fn][r];
        }
    }
}

__global__ __launch_bounds__(256) void reduce_kernel(const float* __restrict__ part,
                                                     float* __restrict__ out) {
    const int gid = blockIdx.x * 256 + threadIdx.x;   // 0..65535 float4 slots
    floatx4 acc = {};
    #pragma unroll
    for (int sp = 0; sp < NSPLIT; ++sp)
        acc += *(const floatx4*)(part + (long)sp * (256 * ODIM) + gid * 4);
    *(floatx4*)(out + gid * 4) = acc;
}

extern "C" void kernel_launch(void* const* d_in, const int* in_sizes, int n_in,
                              void* d_out, int out_size, void* d_ws, size_t ws_size,
                              hipStream_t stream) {
    const float* x = (const float*)d_in[0];   // (256, 512) fp32
    const float* W = (const float*)d_in[1];   // (1024, 131328) fp32
    float* out  = (float*)d_out;              // (256, 1024) fp32
    float* part = (float*)d_ws;               // 64 x 256 x 1024 fp32 = 64 MB

    hipLaunchKernelGGL(selmul_kernel, dim3(NT, NSPLIT), dim3(256), 0, stream, x, W, part);
    hipLaunchKernelGGL(reduce_kernel, dim3(256), dim3(256), 0, stream, part, out);
}